// Round 1
// baseline (192.545 us; speedup 1.0000x reference)
//
#include <hip/hip_runtime.h>
#include <hip/hip_bf16.h>
#include <stdint.h>

// Problem constants (from reference setup_inputs)
#define BATCH 8
#define TC 2048   // M
#define TQ 1024   // K
#define DD 1024   // N

typedef __attribute__((ext_vector_type(8))) __bf16 bf16x8;
typedef __attribute__((ext_vector_type(4))) float f32x4;

__device__ __forceinline__ ushort f2bf(float f) {
    uint32_t u = __float_as_uint(f);
    uint32_t r = (u + 0x7fffu + ((u >> 16) & 1u)) >> 16;  // RNE
    return (ushort)r;
}

// ---------------------------------------------------------------------------
// Kernel 1: row softmax -> bf16 attn.  One block (256 thr) per row of 1024.
// ---------------------------------------------------------------------------
__global__ __launch_bounds__(256) void softmax_rows(const float* __restrict__ sim,
                                                    ushort* __restrict__ attn) {
    const int row = blockIdx.x;
    const int t = threadIdx.x;
    const int w = t >> 6, lane = t & 63;
    const float4 x = ((const float4*)(sim + (size_t)row * TQ))[t];

    float m = fmaxf(fmaxf(x.x, x.y), fmaxf(x.z, x.w));
    #pragma unroll
    for (int o = 32; o >= 1; o >>= 1) m = fmaxf(m, __shfl_xor(m, o));

    __shared__ float smax[4];
    __shared__ float ssum[4];
    if (lane == 0) smax[w] = m;
    __syncthreads();
    m = fmaxf(fmaxf(smax[0], smax[1]), fmaxf(smax[2], smax[3]));

    const float L2E = 1.4426950408889634f;
    float e0 = exp2f((x.x - m) * L2E);
    float e1 = exp2f((x.y - m) * L2E);
    float e2 = exp2f((x.z - m) * L2E);
    float e3 = exp2f((x.w - m) * L2E);

    float s = (e0 + e1) + (e2 + e3);
    #pragma unroll
    for (int o = 32; o >= 1; o >>= 1) s += __shfl_xor(s, o);
    if (lane == 0) ssum[w] = s;
    __syncthreads();
    s = (ssum[0] + ssum[1]) + (ssum[2] + ssum[3]);
    const float inv = 1.0f / s;

    ushort4 o4;
    o4.x = f2bf(e0 * inv);
    o4.y = f2bf(e1 * inv);
    o4.z = f2bf(e2 * inv);
    o4.w = f2bf(e3 * inv);
    ((ushort4*)(attn + (size_t)row * TQ))[t] = o4;
}

// ---------------------------------------------------------------------------
// Kernel 2: qencode [b][q][d] fp32  ->  qT [b][d][q] bf16 (32x32 LDS tiles)
// ---------------------------------------------------------------------------
__global__ __launch_bounds__(256) void transpose_cast(const float* __restrict__ q,
                                                      ushort* __restrict__ qt) {
    __shared__ float tile[32][33];
    const int b = blockIdx.z;
    const int q0 = blockIdx.y * 32;
    const int d0 = blockIdx.x * 32;
    const int t = threadIdx.x;
    const int r = t >> 3;          // 0..31
    const int c = (t & 7) * 4;     // 0..28

    float4 v = *(const float4*)(q + ((size_t)b * TQ + q0 + r) * DD + d0 + c);
    tile[r][c + 0] = v.x;
    tile[r][c + 1] = v.y;
    tile[r][c + 2] = v.z;
    tile[r][c + 3] = v.w;
    __syncthreads();

    const int d = t >> 3;          // output row (d-local)
    const int qq = (t & 7) * 4;    // output col (q-local)
    ushort4 o4;
    o4.x = f2bf(tile[qq + 0][d]);
    o4.y = f2bf(tile[qq + 1][d]);
    o4.z = f2bf(tile[qq + 2][d]);
    o4.w = f2bf(tile[qq + 3][d]);
    *(ushort4*)(qt + ((size_t)b * DD + d0 + d) * TQ + q0 + qq) = o4;
}

// ---------------------------------------------------------------------------
// Kernel 3: batched GEMM  C[b] = A[b] (MxK bf16, row-major)
//                                 x Bt[b]^T (Bt is N x K bf16, row-major)
// 128x128 tile, BK=32, 256 threads = 4 waves, each wave 64x64 via 4x4 MFMAs.
// global_load_lds width-16 staging (wave-uniform LDS base + lane*16).
// ---------------------------------------------------------------------------
__global__ __launch_bounds__(256, 2) void gemm_bf16(const ushort* __restrict__ A,
                                                    const ushort* __restrict__ Bt,
                                                    float* __restrict__ C) {
    __shared__ __align__(16) ushort As[128 * 32];
    __shared__ __align__(16) ushort Bs[128 * 32];

    const int b = blockIdx.z;
    const int tn0 = blockIdx.x * 128;
    const int tm0 = blockIdx.y * 128;
    const ushort* Ab = A + (size_t)b * TC * TQ;
    const ushort* Bb = Bt + (size_t)b * DD * TQ;
    float* Cb = C + (size_t)b * TC * DD;

    const int t = threadIdx.x;
    const int w = t >> 6, lane = t & 63;
    const int quad = lane >> 4, l16 = lane & 15;
    const int wm = (w >> 1) * 64, wn = (w & 1) * 64;

    f32x4 acc[4][4];
    #pragma unroll
    for (int i = 0; i < 4; i++)
        #pragma unroll
        for (int j = 0; j < 4; j++) acc[i][j] = (f32x4){0.f, 0.f, 0.f, 0.f};

    // staging geometry: lane `l` of wave `w`, issue `j` lands at LDS byte
    // j*4096 + w*1024 + l*16  ->  row = j*64 + w*16 + l/4, k = (l&3)*8
    const int srow = w * 16 + (lane >> 2);
    const int sk = (lane & 3) * 8;

    for (int kk = 0; kk < TQ; kk += 32) {
        #pragma unroll
        for (int j = 0; j < 2; j++) {
            const ushort* ga = Ab + (size_t)(tm0 + j * 64 + srow) * TQ + kk + sk;
            const ushort* gb = Bb + (size_t)(tn0 + j * 64 + srow) * TQ + kk + sk;
            char* la = (char*)As + j * 4096 + w * 1024;
            char* lb = (char*)Bs + j * 4096 + w * 1024;
            __builtin_amdgcn_global_load_lds(
                (const __attribute__((address_space(1))) void*)ga,
                (__attribute__((address_space(3))) void*)la, 16, 0, 0);
            __builtin_amdgcn_global_load_lds(
                (const __attribute__((address_space(1))) void*)gb,
                (__attribute__((address_space(3))) void*)lb, 16, 0, 0);
        }
        __syncthreads();

        bf16x8 af[4], bfr[4];
        #pragma unroll
        for (int mi = 0; mi < 4; mi++)
            af[mi] = *(const bf16x8*)&As[(wm + mi * 16 + l16) * 32 + quad * 8];
        #pragma unroll
        for (int ni = 0; ni < 4; ni++)
            bfr[ni] = *(const bf16x8*)&Bs[(wn + ni * 16 + l16) * 32 + quad * 8];

        #pragma unroll
        for (int mi = 0; mi < 4; mi++)
            #pragma unroll
            for (int ni = 0; ni < 4; ni++)
                acc[mi][ni] = __builtin_amdgcn_mfma_f32_16x16x32_bf16(
                    af[mi], bfr[ni], acc[mi][ni], 0, 0, 0);
        __syncthreads();
    }

    // epilogue: C/D layout col=lane&15, row=quad*4+reg
    #pragma unroll
    for (int mi = 0; mi < 4; mi++) {
        const int r0 = tm0 + wm + mi * 16 + quad * 4;
        #pragma unroll
        for (int ni = 0; ni < 4; ni++) {
            const int c = tn0 + wn + ni * 16 + l16;
            f32x4 v = acc[mi][ni];
            #pragma unroll
            for (int r = 0; r < 4; r++) Cb[(size_t)(r0 + r) * DD + c] = v[r];
        }
    }
}

// ---------------------------------------------------------------------------
extern "C" void kernel_launch(void* const* d_in, const int* in_sizes, int n_in,
                              void* d_out, int out_size, void* d_ws, size_t ws_size,
                              hipStream_t stream) {
    const float* sim = (const float*)d_in[0];   // [8, 2048, 1024]
    const float* qen = (const float*)d_in[1];   // [8, 1024, 1024]
    float* out = (float*)d_out;                 // [8, 2048, 1024]

    ushort* attn = (ushort*)d_ws;                                  // 32 MiB bf16
    ushort* qt = (ushort*)d_ws + (size_t)BATCH * TC * TQ;          // 16 MiB bf16

    softmax_rows<<<BATCH * TC, 256, 0, stream>>>(sim, attn);
    transpose_cast<<<dim3(DD / 32, TQ / 32, BATCH), 256, 0, stream>>>(qen, qt);
    gemm_bf16<<<dim3(DD / 128, TC / 128, BATCH), 256, 0, stream>>>(attn, qt, out);
}

// Round 2
// 186.177 us; speedup vs baseline: 1.0342x; 1.0342x over previous
//
#include <hip/hip_runtime.h>
#include <hip/hip_bf16.h>
#include <stdint.h>

// Problem constants (from reference setup_inputs)
#define BATCH 8
#define TC 2048   // M
#define TQ 1024   // K
#define DD 1024   // N

typedef __attribute__((ext_vector_type(8))) __bf16 bf16x8;
typedef __attribute__((ext_vector_type(4))) float f32x4;

__device__ __forceinline__ ushort f2bf(float f) {
    uint32_t u = __float_as_uint(f);
    uint32_t r = (u + 0x7fffu + ((u >> 16) & 1u)) >> 16;  // RNE
    return (ushort)r;
}

// ---------------------------------------------------------------------------
// Kernel 1: row softmax -> bf16 attn.  One WAVE per row of 1024 (no barriers,
// no LDS). Block = 256 thr = 4 waves = 4 rows; grid = 4096.
// ---------------------------------------------------------------------------
__global__ __launch_bounds__(256) void softmax_rows(const float* __restrict__ sim,
                                                    ushort* __restrict__ attn) {
    const int wid = threadIdx.x >> 6;
    const int lane = threadIdx.x & 63;
    const int row = blockIdx.x * 4 + wid;
    const float4* src = (const float4*)(sim + (size_t)row * TQ);

    float4 x[4];
    #pragma unroll
    for (int j = 0; j < 4; j++) x[j] = src[lane + 64 * j];

    float m = -INFINITY;
    #pragma unroll
    for (int j = 0; j < 4; j++)
        m = fmaxf(m, fmaxf(fmaxf(x[j].x, x[j].y), fmaxf(x[j].z, x[j].w)));
    #pragma unroll
    for (int o = 32; o >= 1; o >>= 1) m = fmaxf(m, __shfl_xor(m, o));

    const float L2E = 1.4426950408889634f;
    float e[4][4];
    float s = 0.f;
    #pragma unroll
    for (int j = 0; j < 4; j++) {
        e[j][0] = exp2f((x[j].x - m) * L2E);
        e[j][1] = exp2f((x[j].y - m) * L2E);
        e[j][2] = exp2f((x[j].z - m) * L2E);
        e[j][3] = exp2f((x[j].w - m) * L2E);
        s += (e[j][0] + e[j][1]) + (e[j][2] + e[j][3]);
    }
    #pragma unroll
    for (int o = 32; o >= 1; o >>= 1) s += __shfl_xor(s, o);
    const float inv = 1.0f / s;

    ushort4* dst = (ushort4*)(attn + (size_t)row * TQ);
    #pragma unroll
    for (int j = 0; j < 4; j++) {
        ushort4 o4;
        o4.x = f2bf(e[j][0] * inv);
        o4.y = f2bf(e[j][1] * inv);
        o4.z = f2bf(e[j][2] * inv);
        o4.w = f2bf(e[j][3] * inv);
        dst[lane + 64 * j] = o4;
    }
}

// ---------------------------------------------------------------------------
// Kernel 2: qencode [b][q][d] fp32 -> qT [b][d][q] bf16.  64x64 tiles,
// 256 thr, LDS pad 65 => both LDS store and read are exactly 2-way (free).
// ---------------------------------------------------------------------------
__global__ __launch_bounds__(256) void transpose_cast(const float* __restrict__ q,
                                                      ushort* __restrict__ qt) {
    __shared__ float tile[64][65];
    const int b = blockIdx.z;
    const int q0 = blockIdx.y * 64;
    const int d0 = blockIdx.x * 64;
    const int t = threadIdx.x;
    const int r = t >> 4;          // 0..15
    const int c = (t & 15) * 4;    // 0..60

    #pragma unroll
    for (int it = 0; it < 4; it++) {
        float4 v = *(const float4*)(q + ((size_t)b * TQ + q0 + r + it * 16) * DD + d0 + c);
        tile[r + it * 16][c + 0] = v.x;
        tile[r + it * 16][c + 1] = v.y;
        tile[r + it * 16][c + 2] = v.z;
        tile[r + it * 16][c + 3] = v.w;
    }
    __syncthreads();

    #pragma unroll
    for (int it = 0; it < 4; it++) {
        const int d = (t >> 4) + it * 16;   // d-local
        const int qq = (t & 15) * 4;        // q-local
        ushort4 o4;
        o4.x = f2bf(tile[qq + 0][d]);
        o4.y = f2bf(tile[qq + 1][d]);
        o4.z = f2bf(tile[qq + 2][d]);
        o4.w = f2bf(tile[qq + 3][d]);
        *(ushort4*)(qt + ((size_t)b * DD + d0 + d) * TQ + q0 + qq) = o4;
    }
}

// ---------------------------------------------------------------------------
// Kernel 3: batched GEMM  C[b] = A[b] (MxK bf16) x Bt[b]^T (NxK bf16)
// 128x128 tile, BK=32, 4 waves x (4x4 of 16x16x32 MFMA).
// global_load_lds width-16 staging.  1D grid + swizzle: 32 consecutive
// blocks share 4 m-tiles x 8 n-tiles (3 MiB of operand tiles -> L2 reuse).
// ---------------------------------------------------------------------------
__global__ __launch_bounds__(256, 2) void gemm_bf16(const ushort* __restrict__ A,
                                                    const ushort* __restrict__ Bt,
                                                    float* __restrict__ C) {
    __shared__ __align__(16) ushort As[128 * 32];
    __shared__ __align__(16) ushort Bs[128 * 32];

    const int flat = blockIdx.x;
    const int b = flat >> 7;          // batch
    const int rem = flat & 127;       // 16 m-tiles x 8 n-tiles
    const int group = rem >> 5;       // 4 groups of 32 blocks
    const int mi_t = group * 4 + (rem & 3);
    const int ni_t = (rem >> 2) & 7;
    const int tm0 = mi_t * 128;
    const int tn0 = ni_t * 128;

    const ushort* Ab = A + (size_t)b * TC * TQ;
    const ushort* Bb = Bt + (size_t)b * DD * TQ;
    float* Cb = C + (size_t)b * TC * DD;

    const int t = threadIdx.x;
    const int w = t >> 6, lane = t & 63;
    const int quad = lane >> 4, l16 = lane & 15;
    const int wm = (w >> 1) * 64, wn = (w & 1) * 64;

    f32x4 acc[4][4];
    #pragma unroll
    for (int i = 0; i < 4; i++)
        #pragma unroll
        for (int j = 0; j < 4; j++) acc[i][j] = (f32x4){0.f, 0.f, 0.f, 0.f};

    const int srow = w * 16 + (lane >> 2);
    const int sk = (lane & 3) * 8;

    for (int kk = 0; kk < TQ; kk += 32) {
        #pragma unroll
        for (int j = 0; j < 2; j++) {
            const ushort* ga = Ab + (size_t)(tm0 + j * 64 + srow) * TQ + kk + sk;
            const ushort* gb = Bb + (size_t)(tn0 + j * 64 + srow) * TQ + kk + sk;
            char* la = (char*)As + j * 4096 + w * 1024;
            char* lb = (char*)Bs + j * 4096 + w * 1024;
            __builtin_amdgcn_global_load_lds(
                (const __attribute__((address_space(1))) void*)ga,
                (__attribute__((address_space(3))) void*)la, 16, 0, 0);
            __builtin_amdgcn_global_load_lds(
                (const __attribute__((address_space(1))) void*)gb,
                (__attribute__((address_space(3))) void*)lb, 16, 0, 0);
        }
        __syncthreads();

        bf16x8 af[4], bfr[4];
        #pragma unroll
        for (int mi = 0; mi < 4; mi++)
            af[mi] = *(const bf16x8*)&As[(wm + mi * 16 + l16) * 32 + quad * 8];
        #pragma unroll
        for (int ni = 0; ni < 4; ni++)
            bfr[ni] = *(const bf16x8*)&Bs[(wn + ni * 16 + l16) * 32 + quad * 8];

        #pragma unroll
        for (int mi = 0; mi < 4; mi++)
            #pragma unroll
            for (int ni = 0; ni < 4; ni++)
                acc[mi][ni] = __builtin_amdgcn_mfma_f32_16x16x32_bf16(
                    af[mi], bfr[ni], acc[mi][ni], 0, 0, 0);
        __syncthreads();
    }

    // epilogue: C/D layout col=lane&15, row=quad*4+reg
    #pragma unroll
    for (int mi = 0; mi < 4; mi++) {
        const int r0 = tm0 + wm + mi * 16 + quad * 4;
        #pragma unroll
        for (int ni = 0; ni < 4; ni++) {
            const int c = tn0 + wn + ni * 16 + l16;
            f32x4 v = acc[mi][ni];
            #pragma unroll
            for (int r = 0; r < 4; r++) Cb[(size_t)(r0 + r) * DD + c] = v[r];
        }
    }
}

// ---------------------------------------------------------------------------
extern "C" void kernel_launch(void* const* d_in, const int* in_sizes, int n_in,
                              void* d_out, int out_size, void* d_ws, size_t ws_size,
                              hipStream_t stream) {
    const float* sim = (const float*)d_in[0];   // [8, 2048, 1024]
    const float* qen = (const float*)d_in[1];   // [8, 1024, 1024]
    float* out = (float*)d_out;                 // [8, 2048, 1024]

    ushort* attn = (ushort*)d_ws;                                  // 32 MiB bf16
    ushort* qt = (ushort*)d_ws + (size_t)BATCH * TC * TQ;          // 16 MiB bf16

    softmax_rows<<<BATCH * TC / 4, 256, 0, stream>>>(sim, attn);
    transpose_cast<<<dim3(DD / 64, TQ / 64, BATCH), 256, 0, stream>>>(qen, qt);
    gemm_bf16<<<BATCH * (TC / 128) * (DD / 128), 256, 0, stream>>>(attn, qt, out);
}